// Round 1
// baseline (242.111 us; speedup 1.0000x reference)
//
#include <hip/hip_runtime.h>

// KMeans soft-assignment, fused: logits = (2*x.c - ||c||^2) / T  (||x||^2 cancels in softmax)
// x: [32768, 256] f32, c: [512, 256] f32, out: [32768, 512] f32
#define NROWS 32768
#define KC 512          // clusters
#define DDIM 256        // feature dim
#define TM 16           // rows per block

// ---- kernel 0: csq10[k] = 10 * sum_d c[k][d]^2  (T=0.1 folded in) ----
__global__ void csq_kernel(const float* __restrict__ c, float* __restrict__ csq10) {
    int col = blockIdx.x * blockDim.x + threadIdx.x;
    if (col < KC) {
        const float4* row = (const float4*)(c + (size_t)col * DDIM);
        float s = 0.f;
        #pragma unroll
        for (int i = 0; i < DDIM / 4; ++i) {
            float4 v = row[i];
            s += v.x * v.x + v.y * v.y + v.z * v.z + v.w * v.w;
        }
        csq10[col] = 10.0f * s;
    }
}

#define FMA4(acc, s, v)                      \
    do {                                     \
        (acc).x = fmaf((s), (v).x, (acc).x); \
        (acc).y = fmaf((s), (v).y, (acc).y); \
        (acc).z = fmaf((s), (v).z, (acc).z); \
        (acc).w = fmaf((s), (v).w, (acc).w); \
    } while (0)

// ---- kernel 1: fused distances + softmax ----
// block: 256 threads (4 waves), tile: 16 rows x 512 cols
// thread (ty=tid>>6, tx=tid&63): rows ty*4..+3, cols [tx*4..+3] and [tx*4+256..+3]
__global__ __launch_bounds__(256) void kmeans_fused(
    const float* __restrict__ x, const float* __restrict__ c,
    const float* __restrict__ csq10, float* __restrict__ out) {
    __shared__ float xs[TM][DDIM];   // 16 KB, x tile
    __shared__ float cs[16][KC];     // 32 KB, centroid chunk (d-major); reused as logits[TM][KC]

    const int tid  = threadIdx.x;
    const int row0 = blockIdx.x * TM;

    // load x tile (coalesced float4)
    {
        const float4* xg  = (const float4*)(x + (size_t)row0 * DDIM);
        float4*       xsv = (float4*)(&xs[0][0]);
        #pragma unroll
        for (int i = 0; i < 4; ++i) xsv[tid + i * 256] = xg[tid + i * 256];
    }

    const int ty   = tid >> 6;   // wave id, row group
    const int tx   = tid & 63;   // lane
    const int colA = tx * 4;

    float4 accA[4] = {make_float4(0,0,0,0), make_float4(0,0,0,0), make_float4(0,0,0,0), make_float4(0,0,0,0)};
    float4 accB[4] = {make_float4(0,0,0,0), make_float4(0,0,0,0), make_float4(0,0,0,0), make_float4(0,0,0,0)};

    for (int ch = 0; ch < DDIM / 16; ++ch) {
        const int d0 = ch * 16;
        __syncthreads();  // xs ready (ch=0); cs safe to overwrite (ch>0)
        // stage c[*, d0..d0+16) into cs[dd][col] (transpose on store; stores conflict-free)
        #pragma unroll
        for (int i = 0; i < 8; ++i) {
            int    f   = tid + i * 256;      // 0..2047
            int    col = f & (KC - 1);
            int    q   = f >> 9;             // 0..3
            float4 v   = *(const float4*)(c + (size_t)col * DDIM + d0 + q * 4);
            cs[q * 4 + 0][col] = v.x;
            cs[q * 4 + 1][col] = v.y;
            cs[q * 4 + 2][col] = v.z;
            cs[q * 4 + 3][col] = v.w;
        }
        __syncthreads();
        #pragma unroll
        for (int dd = 0; dd < 16; dd += 4) {
            float4 xv[4];
            #pragma unroll
            for (int r = 0; r < 4; ++r)
                xv[r] = *(const float4*)(&xs[ty * 4 + r][d0 + dd]);  // broadcast within wave
            #pragma unroll
            for (int k = 0; k < 4; ++k) {
                float4 cA = *(const float4*)(&cs[dd + k][colA]);         // dense b128
                float4 cB = *(const float4*)(&cs[dd + k][colA + 256]);
                #pragma unroll
                for (int r = 0; r < 4; ++r) {
                    const float* xf = (const float*)&xv[r];
                    float        xk = xf[k];
                    FMA4(accA[r], xk, cA);
                    FMA4(accB[r], xk, cB);
                }
            }
        }
    }
    __syncthreads();

    // logits into cs (reuse): logit = 20*cross - 10*csq
    {
        float4 qA = *(const float4*)(csq10 + colA);
        float4 qB = *(const float4*)(csq10 + colA + 256);
        #pragma unroll
        for (int r = 0; r < 4; ++r) {
            int    row = ty * 4 + r;
            float4 la, lb;
            la.x = 20.f * accA[r].x - qA.x;
            la.y = 20.f * accA[r].y - qA.y;
            la.z = 20.f * accA[r].z - qA.z;
            la.w = 20.f * accA[r].w - qA.w;
            lb.x = 20.f * accB[r].x - qB.x;
            lb.y = 20.f * accB[r].y - qB.y;
            lb.z = 20.f * accB[r].z - qB.z;
            lb.w = 20.f * accB[r].w - qB.w;
            *(float4*)&cs[row][colA]       = la;
            *(float4*)&cs[row][colA + 256] = lb;
        }
    }
    __syncthreads();

    // softmax: wave ty handles rows ty*4..+3; lane covers cols [lane*4..+3] and [+256..+3]
    #pragma unroll
    for (int r = 0; r < 4; ++r) {
        int    row = ty * 4 + r;
        float4 va  = *(const float4*)(&cs[row][tx * 4]);
        float4 vb  = *(const float4*)(&cs[row][tx * 4 + 256]);
        float  m   = fmaxf(fmaxf(fmaxf(va.x, va.y), fmaxf(va.z, va.w)),
                           fmaxf(fmaxf(vb.x, vb.y), fmaxf(vb.z, vb.w)));
        #pragma unroll
        for (int off = 32; off > 0; off >>= 1) m = fmaxf(m, __shfl_xor(m, off));
        float e0 = __expf(va.x - m), e1 = __expf(va.y - m), e2 = __expf(va.z - m), e3 = __expf(va.w - m);
        float e4 = __expf(vb.x - m), e5 = __expf(vb.y - m), e6 = __expf(vb.z - m), e7 = __expf(vb.w - m);
        float s  = ((e0 + e1) + (e2 + e3)) + ((e4 + e5) + (e6 + e7));
        #pragma unroll
        for (int off = 32; off > 0; off >>= 1) s += __shfl_xor(s, off);
        float  inv  = 1.0f / s;
        float4 oa   = make_float4(e0 * inv, e1 * inv, e2 * inv, e3 * inv);
        float4 ob   = make_float4(e4 * inv, e5 * inv, e6 * inv, e7 * inv);
        float* orow = out + (size_t)(row0 + row) * KC;
        *(float4*)(orow + tx * 4)       = oa;
        *(float4*)(orow + tx * 4 + 256) = ob;
    }
}

extern "C" void kernel_launch(void* const* d_in, const int* in_sizes, int n_in,
                              void* d_out, int out_size, void* d_ws, size_t ws_size,
                              hipStream_t stream) {
    const float* x     = (const float*)d_in[0];
    const float* c     = (const float*)d_in[1];
    float*       out   = (float*)d_out;
    float*       csq10 = (float*)d_ws;  // 512 floats

    csq_kernel<<<2, 256, 0, stream>>>(c, csq10);
    kmeans_fused<<<NROWS / TM, 256, 0, stream>>>(x, c, csq10, out);
}

// Round 2
// 227.632 us; speedup vs baseline: 1.0636x; 1.0636x over previous
//
#include <hip/hip_runtime.h>

// KMeans soft-assignment via bf16 hi/lo split MFMA.
// logits = (2*x.c - ||c||^2)/T  (||x||^2 cancels in softmax), T=0.1
// cross ~= x_hi*c_hi + x_hi*c_lo + x_lo*c_hi   (bf16 split, fp32 accumulate)
// x: [32768,256] f32, c: [512,256] f32, out: [32768,512] f32
#define NROWS 32768
#define KC 512
#define DDIM 256
#define BM 64          // rows per block
#define BK 32          // k-chunk (one mfma K)

typedef __attribute__((ext_vector_type(8))) short bf16x8;   // 8 bf16 = 4 VGPRs
typedef __attribute__((ext_vector_type(4))) float f32x4;

__device__ __forceinline__ unsigned short f2bf(float f) {   // RNE f32->bf16
    union { float f; unsigned int u; } a; a.f = f;
    unsigned int r = a.u + 0x7fffu + ((a.u >> 16) & 1u);
    return (unsigned short)(r >> 16);
}
__device__ __forceinline__ float bf2f(unsigned short h) {
    union { unsigned int u; float f; } a; a.u = ((unsigned int)h) << 16;
    return a.f;
}
// async global->LDS, 16B per lane; LDS dst = uniform base + lane*16
__device__ __forceinline__ void ld16(const void* g, void* l) {
    __builtin_amdgcn_global_load_lds(
        (const __attribute__((address_space(1))) unsigned int*)g,
        (__attribute__((address_space(3))) unsigned int*)l, 16, 0, 0);
}

// ---- prep: c f32 -> c_hi/c_lo bf16 [512][256] + csq10[k] = 10*||c_k||^2 ----
__global__ __launch_bounds__(64) void prep_c(const float* __restrict__ c,
                                             unsigned short* __restrict__ chi,
                                             unsigned short* __restrict__ clo,
                                             float* __restrict__ csq10) {
    const int row = blockIdx.x, lane = threadIdx.x;   // 512 blocks x 64 threads
    float4 v = ((const float4*)(c + (size_t)row * DDIM))[lane];
    float vv[4] = {v.x, v.y, v.z, v.w};
    unsigned short hh[4], ll[4];
    float ssq = 0.f;
    #pragma unroll
    for (int i = 0; i < 4; ++i) {
        ssq += vv[i] * vv[i];
        hh[i] = f2bf(vv[i]);
        ll[i] = f2bf(vv[i] - bf2f(hh[i]));
    }
    #pragma unroll
    for (int off = 32; off; off >>= 1) ssq += __shfl_xor(ssq, off);
    if (lane == 0) csq10[row] = 10.f * ssq;
    *(ushort4*)(chi + (size_t)row * DDIM + lane * 4) = make_ushort4(hh[0], hh[1], hh[2], hh[3]);
    *(ushort4*)(clo + (size_t)row * DDIM + lane * 4) = make_ushort4(ll[0], ll[1], ll[2], ll[3]);
}

// ---- main: 512 blocks x 512 threads (8 waves: 4 M-groups x 2 N-groups) ----
// wave (wm,wn): rows wm*16..+15, cols wn*256..+255 (16 col-tiles of 16)
// LDS swizzle: quad slot s = q ^ ((row>>1)&3)  -> 2-way (free) b128 conflicts
__global__ __launch_bounds__(512, 4) void kmeans_mfma(
    const float* __restrict__ x, const unsigned short* __restrict__ chi,
    const unsigned short* __restrict__ clo, const float* __restrict__ csq10,
    float* __restrict__ out) {
    __shared__ __align__(16) unsigned short Ahi[BM * BK], Alo[BM * BK];   // 4 KB each
    __shared__ __align__(16) unsigned short Bhi[KC * BK], Blo[KC * BK];   // 32 KB each
    __shared__ float red[2][2][BM];                                       // 1 KB

    const int tid  = threadIdx.x;
    const int w    = tid >> 6, lane = tid & 63;
    const int wm   = w >> 1, wn = w & 1;
    const int cc   = lane & 15, q = lane >> 4;
    const int row0 = blockIdx.x * BM;

    f32x4 acc[16];
    #pragma unroll
    for (int t = 0; t < 16; ++t) acc[t] = (f32x4){0.f, 0.f, 0.f, 0.f};

    // x staging: thread -> (row xr, 4 cols at xc)
    const int    xr   = tid >> 3;
    const int    xc   = (tid & 7) << 2;
    const float* xptr = x + (size_t)(row0 + xr) * DDIM + xc;
    const int    sAw  = (xc >> 3) ^ ((xr >> 1) & 3);
    unsigned short* aHiW = &Ahi[xr * BK + sAw * 8 + (xc & 4)];
    unsigned short* aLoW = &Alo[xr * BK + sAw * 8 + (xc & 4)];

    // B staging lanes: instr i covers rows (w*4+i)*16..+15, 4 lanes/row
    int nb[4], qb[4];
    #pragma unroll
    for (int i = 0; i < 4; ++i) {
        nb[i] = (w * 4 + i) * 16 + (lane >> 2);
        qb[i] = (lane & 3) ^ ((nb[i] >> 1) & 3);
    }

    // fragment read pointers (swizzled slot identical for A and B: wm*8, wn*128 are 0 mod 4)
    const int             sF    = q ^ ((cc >> 1) & 3);
    const unsigned short* aHiR  = &Ahi[(wm * 16 + cc) * BK + sF * 8];
    const unsigned short* aLoR  = &Alo[(wm * 16 + cc) * BK + sF * 8];
    const int             bbase = wn * 256 + cc;   // this lane's column base

    float4 xv = *(const float4*)xptr;

    for (int ks = 0; ks < DDIM / BK; ++ks) {
        const int k0 = ks * BK;
        __syncthreads();   // previous compute done
        #pragma unroll
        for (int i = 0; i < 4; ++i) {
            ld16(chi + (size_t)nb[i] * DDIM + k0 + qb[i] * 8, &Bhi[(w * 4 + i) * 512]);
            ld16(clo + (size_t)nb[i] * DDIM + k0 + qb[i] * 8, &Blo[(w * 4 + i) * 512]);
        }
        {
            float          vv[4] = {xv.x, xv.y, xv.z, xv.w};
            unsigned short hh[4], ll[4];
            #pragma unroll
            for (int i = 0; i < 4; ++i) {
                hh[i] = f2bf(vv[i]);
                ll[i] = f2bf(vv[i] - bf2f(hh[i]));
            }
            *(ushort4*)aHiW = make_ushort4(hh[0], hh[1], hh[2], hh[3]);
            *(ushort4*)aLoW = make_ushort4(ll[0], ll[1], ll[2], ll[3]);
        }
        if (ks < DDIM / BK - 1) xv = *(const float4*)(xptr + k0 + BK);  // prefetch
        __syncthreads();   // staging visible

        bf16x8 ah = *(const bf16x8*)aHiR;
        bf16x8 al = *(const bf16x8*)aLoR;
        #pragma unroll
        for (int t = 0; t < 16; ++t) {
            bf16x8 b = *(const bf16x8*)&Bhi[(bbase + t * 16) * BK + sF * 8];
            acc[t]   = __builtin_amdgcn_mfma_f32_16x16x32_bf16(ah, b, acc[t], 0, 0, 0);
        }
        #pragma unroll
        for (int t = 0; t < 16; ++t) {
            bf16x8 b = *(const bf16x8*)&Blo[(bbase + t * 16) * BK + sF * 8];
            acc[t]   = __builtin_amdgcn_mfma_f32_16x16x32_bf16(ah, b, acc[t], 0, 0, 0);
        }
        #pragma unroll
        for (int t = 0; t < 16; ++t) {
            bf16x8 b = *(const bf16x8*)&Bhi[(bbase + t * 16) * BK + sF * 8];
            acc[t]   = __builtin_amdgcn_mfma_f32_16x16x32_bf16(al, b, acc[t], 0, 0, 0);
        }
    }

    // ---- fused softmax epilogue ----
    // lane holds rows rbase..rbase+3 (g) x cols bbase + t*16 (t)
    float csqv[16];
    #pragma unroll
    for (int t = 0; t < 16; ++t) csqv[t] = csq10[bbase + t * 16];
    const int rbase = wm * 16 + q * 4;
    float     M[4], Sv[4];
    #pragma unroll
    for (int g = 0; g < 4; ++g) {
        float pm = -1e30f;
        #pragma unroll
        for (int t = 0; t < 16; ++t) pm = fmaxf(pm, 20.f * acc[t][g] - csqv[t]);
        #pragma unroll
        for (int off = 1; off < 16; off <<= 1) pm = fmaxf(pm, __shfl_xor(pm, off));
        if (cc == 0) red[0][wn][rbase + g] = pm;
        M[g] = pm;
    }
    __syncthreads();
    #pragma unroll
    for (int g = 0; g < 4; ++g) {
        M[g]     = fmaxf(M[g], red[0][1 - wn][rbase + g]);
        float ps = 0.f;
        #pragma unroll
        for (int t = 0; t < 16; ++t) ps += __expf(20.f * acc[t][g] - csqv[t] - M[g]);
        #pragma unroll
        for (int off = 1; off < 16; off <<= 1) ps += __shfl_xor(ps, off);
        if (cc == 0) red[1][wn][rbase + g] = ps;
        Sv[g] = ps;
    }
    __syncthreads();
    #pragma unroll
    for (int g = 0; g < 4; ++g) {
        float  inv  = 1.f / (Sv[g] + red[1][1 - wn][rbase + g]);
        float* orow = out + (size_t)(row0 + rbase + g) * KC + bbase;
        #pragma unroll
        for (int t = 0; t < 16; ++t)
            orow[t * 16] = __expf(20.f * acc[t][g] - csqv[t] - M[g]) * inv;
    }
}

extern "C" void kernel_launch(void* const* d_in, const int* in_sizes, int n_in,
                              void* d_out, int out_size, void* d_ws, size_t ws_size,
                              hipStream_t stream) {
    const float* x   = (const float*)d_in[0];
    const float* c   = (const float*)d_in[1];
    float*       out = (float*)d_out;

    unsigned short* chi   = (unsigned short*)d_ws;        // 256 KB
    unsigned short* clo   = chi + (size_t)KC * DDIM;      // 256 KB
    float*          csq10 = (float*)(clo + (size_t)KC * DDIM);  // 2 KB

    prep_c<<<KC, 64, 0, stream>>>(c, chi, clo, csq10);
    kmeans_mfma<<<NROWS / BM, 512, 0, stream>>>(x, chi, clo, csq10, out);
}

// Round 3
// 194.069 us; speedup vs baseline: 1.2476x; 1.1729x over previous
//
#include <hip/hip_runtime.h>

// KMeans soft-assignment via bf16 hi/lo split MFMA (3 passes), fused softmax.
// logits = (2*x.c - ||c||^2)/T, T=0.1; ||x||^2 cancels in softmax.
// x: [32768,256] f32, c: [512,256] f32, out: [32768,512] f32
#define NROWS 32768
#define KC 512
#define DDIM 256
#define BM 64
#define BK 32
#define KCH (DDIM / BK)        // 8 k-chunks
#define CHUNK_USH (KC * BK)    // 16384 ushorts = 32 KB per chunk

typedef __attribute__((ext_vector_type(8))) short bf16x8;
typedef __attribute__((ext_vector_type(4))) float f32x4;

__device__ __forceinline__ unsigned short f2bf(float f) {   // RNE f32->bf16
    union { float f; unsigned int u; } a; a.f = f;
    unsigned int r = a.u + 0x7fffu + ((a.u >> 16) & 1u);
    return (unsigned short)(r >> 16);
}
__device__ __forceinline__ float bf2f(unsigned short h) {
    union { unsigned int u; float f; } a; a.u = ((unsigned int)h) << 16;
    return a.f;
}
__device__ __forceinline__ void ld16(const void* g, void* l) {
    __builtin_amdgcn_global_load_lds(
        (const __attribute__((address_space(1))) unsigned int*)g,
        (__attribute__((address_space(3))) unsigned int*)l, 16, 0, 0);
}

// ---- prep: c -> chunk-major, LDS-swizzle-baked bf16 hi/lo + csq10 ----
// octet (row n, q) stored at chunk offset (n*4 + (q ^ ((n>>1)&3)))*8 ushorts
__global__ __launch_bounds__(64) void prep_c(const float* __restrict__ c,
                                             unsigned short* __restrict__ bhi,
                                             unsigned short* __restrict__ blo,
                                             float* __restrict__ csq10) {
    const int n = blockIdx.x, lane = threadIdx.x;
    const int d0 = lane * 4;
    float4 v = ((const float4*)(c + (size_t)n * DDIM))[lane];
    float vv[4] = {v.x, v.y, v.z, v.w};
    unsigned short hh[4], ll[4];
    float ssq = 0.f;
    #pragma unroll
    for (int i = 0; i < 4; ++i) {
        ssq += vv[i] * vv[i];
        hh[i] = f2bf(vv[i]);
        ll[i] = f2bf(vv[i] - bf2f(hh[i]));
    }
    #pragma unroll
    for (int off = 32; off; off >>= 1) ssq += __shfl_xor(ssq, off);
    if (lane == 0) csq10[n] = 10.f * ssq;
    const int ks = d0 >> 5;
    const int q  = (d0 >> 3) & 3;
    const int s  = q ^ ((n >> 1) & 3);
    const size_t dst = (size_t)ks * CHUNK_USH + (n * 4 + s) * 8 + (d0 & 7);
    *(ushort4*)(bhi + dst) = make_ushort4(hh[0], hh[1], hh[2], hh[3]);
    *(ushort4*)(blo + dst) = make_ushort4(ll[0], ll[1], ll[2], ll[3]);
}

// ---- main: 512 blocks x 512 threads (8 waves = 4 M-groups x 2 N-groups) ----
union SmemU {
    struct {
        unsigned short Ahi[BM * BK];   // 4 KB
        unsigned short Alo[BM * BK];   // 4 KB
        unsigned short Bhi[KC * BK];   // 32 KB
        unsigned short Blo[KC * BK];   // 32 KB
    } k;
    float lbuf[32 * 516];              // 64.5 KB (pad 516 -> 2-way banks, free)
};

__global__ __launch_bounds__(512, 4) void kmeans_mfma(
    const float* __restrict__ x, const unsigned short* __restrict__ bhi,
    const unsigned short* __restrict__ blo, const float* __restrict__ csq10,
    float* __restrict__ out) {
    __shared__ __align__(16) SmemU sm;
    __shared__ float red[2][2][BM];
    __shared__ float invS[BM];

    const int tid  = threadIdx.x;
    const int w    = tid >> 6, lane = tid & 63;
    const int wm   = w >> 1, wn = w & 1;
    const int cc   = lane & 15, q = lane >> 4;
    const int row0 = blockIdx.x * BM;

    f32x4 acc[16];
    #pragma unroll
    for (int t = 0; t < 16; ++t) acc[t] = (f32x4){0.f, 0.f, 0.f, 0.f};

    // A staging: thread -> (row xr, 4 k's at xc)
    const int    xr   = tid >> 3;
    const int    xc   = (tid & 7) << 2;
    const float* xptr = x + (size_t)(row0 + xr) * DDIM + xc;
    const int    sAw  = (xc >> 3) ^ ((xr >> 1) & 3);
    unsigned short* aHiW = &sm.k.Ahi[xr * BK + sAw * 8 + (xc & 4)];
    unsigned short* aLoW = &sm.k.Alo[xr * BK + sAw * 8 + (xc & 4)];

    // fragment read pointers
    const int             sF   = q ^ ((cc >> 1) & 3);
    const unsigned short* aHiR = &sm.k.Ahi[(wm * 16 + cc) * BK + sF * 8];
    const unsigned short* aLoR = &sm.k.Alo[(wm * 16 + cc) * BK + sF * 8];
    const int             bbase = wn * 256 + cc;

    float4 xv = *(const float4*)xptr;

    for (int ks = 0; ks < KCH; ++ks) {
        __syncthreads();   // previous compute done
        // B staging: fully contiguous 1 KB per instr (layout pre-swizzled by prep)
        {
            const size_t cb = (size_t)ks * CHUNK_USH;
            #pragma unroll
            for (int j = 0; j < 4; ++j) {
                const size_t o = (size_t)(w * 4 + j) * 512;  // ushorts
                ld16(bhi + cb + o + lane * 8, &sm.k.Bhi[o]);
                ld16(blo + cb + o + lane * 8, &sm.k.Blo[o]);
            }
        }
        // A staging: f32 -> hi/lo bf16, swizzled ushort4 write
        {
            float          vv[4] = {xv.x, xv.y, xv.z, xv.w};
            unsigned short hh[4], ll[4];
            #pragma unroll
            for (int i = 0; i < 4; ++i) {
                hh[i] = f2bf(vv[i]);
                ll[i] = f2bf(vv[i] - bf2f(hh[i]));
            }
            *(ushort4*)aHiW = make_ushort4(hh[0], hh[1], hh[2], hh[3]);
            *(ushort4*)aLoW = make_ushort4(ll[0], ll[1], ll[2], ll[3]);
        }
        if (ks < KCH - 1) xv = *(const float4*)(xptr + (ks + 1) * BK);
        __syncthreads();   // staging visible

        bf16x8 ah = *(const bf16x8*)aHiR;
        bf16x8 al = *(const bf16x8*)aLoR;
        #pragma unroll
        for (int t = 0; t < 16; ++t) {
            bf16x8 b = *(const bf16x8*)&sm.k.Bhi[(bbase + t * 16) * BK + sF * 8];
            acc[t]   = __builtin_amdgcn_mfma_f32_16x16x32_bf16(ah, b, acc[t], 0, 0, 0);
        }
        #pragma unroll
        for (int t = 0; t < 16; ++t) {
            bf16x8 b = *(const bf16x8*)&sm.k.Blo[(bbase + t * 16) * BK + sF * 8];
            acc[t]   = __builtin_amdgcn_mfma_f32_16x16x32_bf16(ah, b, acc[t], 0, 0, 0);
        }
        #pragma unroll
        for (int t = 0; t < 16; ++t) {
            bf16x8 b = *(const bf16x8*)&sm.k.Bhi[(bbase + t * 16) * BK + sF * 8];
            acc[t]   = __builtin_amdgcn_mfma_f32_16x16x32_bf16(al, b, acc[t], 0, 0, 0);
        }
    }

    // ---- softmax stats ----
    float csqv[16];
    #pragma unroll
    for (int t = 0; t < 16; ++t) csqv[t] = csq10[bbase + t * 16];
    const int rbase = wm * 16 + q * 4;
    float     M[4];
    #pragma unroll
    for (int g = 0; g < 4; ++g) {
        float pm = -1e30f;
        #pragma unroll
        for (int t = 0; t < 16; ++t) pm = fmaxf(pm, 20.f * acc[t][g] - csqv[t]);
        #pragma unroll
        for (int off = 1; off < 16; off <<= 1) pm = fmaxf(pm, __shfl_xor(pm, off));
        if (cc == 0) red[0][wn][rbase + g] = pm;
        M[g] = pm;
    }
    __syncthreads();
    #pragma unroll
    for (int g = 0; g < 4; ++g) {
        M[g]     = fmaxf(M[g], red[0][1 - wn][rbase + g]);
        float ps = 0.f;
        #pragma unroll
        for (int t = 0; t < 16; ++t) ps += __expf(20.f * acc[t][g] - csqv[t] - M[g]);
        #pragma unroll
        for (int off = 1; off < 16; off <<= 1) ps += __shfl_xor(ps, off);
        if (cc == 0) red[1][wn][rbase + g] = ps;
    }
    __syncthreads();
    if (tid < BM) invS[tid] = 1.f / (red[1][0][tid] + red[1][1][tid]);
    __syncthreads();

    // ---- transpose epilogue: 2 passes of 32 rows through lbuf ----
    #pragma unroll
    for (int p = 0; p < 2; ++p) {
        if ((wm >> 1) == p) {
            const int lr = (wm & 1) * 16 + q * 4;
            #pragma unroll
            for (int g = 0; g < 4; ++g) {
                float mg = M[g];
                #pragma unroll
                for (int t = 0; t < 16; ++t)
                    sm.lbuf[(lr + g) * 516 + wn * 256 + t * 16 + cc] =
                        __expf(20.f * acc[t][g] - csqv[t] - mg);
            }
        }
        __syncthreads();
        #pragma unroll
        for (int j = 0; j < 8; ++j) {
            const int   f    = j * 512 + tid;     // 0..4095 float4 slots
            const int   lrow = f >> 7;            // 0..31
            const int   c4   = f & 127;
            float4      v    = *(const float4*)&sm.lbuf[lrow * 516 + c4 * 4];
            const float inv  = invS[p * 32 + lrow];
            *(float4*)(out + (size_t)(row0 + p * 32 + lrow) * KC + c4 * 4) =
                make_float4(v.x * inv, v.y * inv, v.z * inv, v.w * inv);
        }
        __syncthreads();
    }
}

extern "C" void kernel_launch(void* const* d_in, const int* in_sizes, int n_in,
                              void* d_out, int out_size, void* d_ws, size_t ws_size,
                              hipStream_t stream) {
    const float* x   = (const float*)d_in[0];
    const float* c   = (const float*)d_in[1];
    float*       out = (float*)d_out;

    unsigned short* bhi   = (unsigned short*)d_ws;                 // 256 KB
    unsigned short* blo   = bhi + (size_t)KCH * CHUNK_USH;         // 256 KB
    float*          csq10 = (float*)(blo + (size_t)KCH * CHUNK_USH);  // 2 KB

    prep_c<<<KC, 64, 0, stream>>>(c, bhi, blo, csq10);
    kmeans_mfma<<<NROWS / BM, 512, 0, stream>>>(x, bhi, blo, csq10, out);
}